// Round 1
// baseline (2321.177 us; speedup 1.0000x reference)
//
#include <hip/hip_runtime.h>

#define N_NODES 50000
#define N_EDGES 600000
#define N_GRAPHS 64
#define HID 128
#define OUT_C 32

// ---------------- weight prep: Wt[256][128], Wt[k][j] = k<128 ? Wl[j][k] : Wr[j][k-128]
__global__ void build_wt(const float* __restrict__ Wl, const float* __restrict__ Wr,
                         float* __restrict__ Wt) {
    int idx = blockIdx.x * 256 + threadIdx.x;   // 0..32767
    int k = idx >> 7, j = idx & 127;
    Wt[idx] = (k < 128) ? Wl[j * 128 + k] : Wr[j * 128 + (k - 128)];
}

__global__ void deg_kernel(const int* __restrict__ dst, float* __restrict__ degf, int E) {
    int e = blockIdx.x * 256 + threadIdx.x;
    if (e < E) atomicAdd(&degf[dst[e]], 1.0f);
}

__global__ void invdeg_kernel(const float* __restrict__ degf, float* __restrict__ invdeg, int N) {
    int i = blockIdx.x * 256 + threadIdx.x;
    if (i < N) invdeg[i] = 1.0f / fmaxf(degf[i], 1.0f);
}

// one edge handled by 32 threads, 4 channels each (float4 gather + 4 atomics)
__global__ void scatter_kernel(const float* __restrict__ feat, const int* __restrict__ src,
                               const int* __restrict__ dst, float* __restrict__ msg, int E) {
    long long idx = (long long)blockIdx.x * 256 + threadIdx.x;
    int e = (int)(idx >> 5);
    if (e >= E) return;
    int q = (int)(idx & 31);
    int s = src[e], d = dst[e];
    const float4 v = *(const float4*)(feat + (size_t)s * 128 + q * 4);
    float* p = msg + (size_t)d * 128 + q * 4;
    atomicAdd(p + 0, v.x);
    atomicAdd(p + 1, v.y);
    atomicAdd(p + 2, v.z);
    atomicAdd(p + 3, v.w);
}

// ---------------- fused SAGE layer GEMM:
// out[i][j] = relu(bias[j] + sum_{k<128} msg[i][k]*invdeg[i]*Wt[k][j]
//                          + sum_{k>=128} feat[i][k-128]*Wt[k][j])
// M=50000, N=128, K=256.  BM=64, BN=128, BK=32, 256 threads, 4x8 register tile.
#define BM 64
#define BN 128
#define BK 32

__global__ __launch_bounds__(256) void sage_gemm(
    const float* __restrict__ msg, const float* __restrict__ invdeg,
    const float* __restrict__ feat, const float* __restrict__ Wt,
    const float* __restrict__ bias, float* __restrict__ out, int M) {
    __shared__ float At[BK][BM + 4];   // pad 4 keeps float4 alignment, breaks conflicts
    __shared__ float Bt[BK][BN];

    const int tid = threadIdx.x;
    const int row0 = blockIdx.x * BM;
    const int tn = tid & 15;    // 16 threads over N, 8 cols each
    const int tm = tid >> 4;    // 16 threads over M, 4 rows each
    const int j0 = tn * 8;

    float acc[4][8];
#pragma unroll
    for (int m = 0; m < 4; ++m)
#pragma unroll
        for (int n = 0; n < 8; ++n) acc[m][n] = 0.0f;

    const int alr = tid >> 3;          // 0..31
    const int alc = (tid & 7) * 4;     // 0,4,..,28
    const int bbr = tid >> 5;          // 0..7
    const int bbc = (tid & 31) * 4;    // 0..124

    for (int k0 = 0; k0 < 256; k0 += BK) {
        // ---- load A tile (64 rows x 32 k), transposed into At[k][m]
#pragma unroll
        for (int rr = 0; rr < 2; ++rr) {
            int r = alr + rr * 32;
            int gi = row0 + r;
            float4 v = make_float4(0.f, 0.f, 0.f, 0.f);
            if (gi < M) {
                if (k0 < 128) {
                    v = *(const float4*)(msg + (size_t)gi * 128 + k0 + alc);
                    float s = invdeg[gi];
                    v.x *= s; v.y *= s; v.z *= s; v.w *= s;
                } else {
                    v = *(const float4*)(feat + (size_t)gi * 128 + (k0 - 128) + alc);
                }
            }
            At[alc + 0][r] = v.x;
            At[alc + 1][r] = v.y;
            At[alc + 2][r] = v.z;
            At[alc + 3][r] = v.w;
        }
        // ---- load B tile (32 k x 128 j), already k-major in Wt
#pragma unroll
        for (int rr = 0; rr < 4; ++rr) {
            int r = bbr + rr * 8;
            *(float4*)&Bt[r][bbc] = *(const float4*)(Wt + (size_t)(k0 + r) * 128 + bbc);
        }
        __syncthreads();

#pragma unroll
        for (int kk = 0; kk < BK; ++kk) {
            const float4 av = *(const float4*)&At[kk][tm * 4];
            const float4 b0 = *(const float4*)&Bt[kk][j0];
            const float4 b1 = *(const float4*)&Bt[kk][j0 + 4];
            const float a4[4] = {av.x, av.y, av.z, av.w};
            const float b8[8] = {b0.x, b0.y, b0.z, b0.w, b1.x, b1.y, b1.z, b1.w};
#pragma unroll
            for (int m = 0; m < 4; ++m)
#pragma unroll
                for (int n = 0; n < 8; ++n) acc[m][n] += a4[m] * b8[n];
        }
        __syncthreads();
    }

    float bv[8];
#pragma unroll
    for (int n = 0; n < 8; ++n) bv[n] = bias[j0 + n];

#pragma unroll
    for (int m = 0; m < 4; ++m) {
        int gi = row0 + tm * 4 + m;
        if (gi < M) {
            float4 o0, o1;
            o0.x = fmaxf(acc[m][0] + bv[0], 0.f);
            o0.y = fmaxf(acc[m][1] + bv[1], 0.f);
            o0.z = fmaxf(acc[m][2] + bv[2], 0.f);
            o0.w = fmaxf(acc[m][3] + bv[3], 0.f);
            o1.x = fmaxf(acc[m][4] + bv[4], 0.f);
            o1.y = fmaxf(acc[m][5] + bv[5], 0.f);
            o1.z = fmaxf(acc[m][6] + bv[6], 0.f);
            o1.w = fmaxf(acc[m][7] + bv[7], 0.f);
            *(float4*)(out + (size_t)gi * 128 + j0) = o0;
            *(float4*)(out + (size_t)gi * 128 + j0 + 4) = o1;
        }
    }
}

// ---------------- pooling: batch is sorted; run-length accumulate, flush on change
#define POOL_CHUNK 128
__global__ void pool_kernel(const float* __restrict__ h, const int* __restrict__ batch,
                            float* __restrict__ pooled, float* __restrict__ cntf, int N) {
    int c = threadIdx.x;               // 0..127
    int n0 = blockIdx.x * POOL_CHUNK;
    int n1 = min(n0 + POOL_CHUNK, N);
    if (n0 >= N) return;
    float run = 0.0f;
    float runc = 0.0f;
    int curg = batch[n0];
    for (int n = n0; n < n1; ++n) {
        int g = batch[n];
        if (g != curg) {
            atomicAdd(&pooled[curg * 128 + c], run);
            if (c == 0) atomicAdd(&cntf[curg], runc);
            run = 0.0f; runc = 0.0f; curg = g;
        }
        run += h[(size_t)n * 128 + c];
        runc += 1.0f;
    }
    atomicAdd(&pooled[curg * 128 + c], run);
    if (c == 0) atomicAdd(&cntf[curg], runc);
}

// ---------------- final linear: out[g][j] = blin[j] + sum_c pooled[g][c]/cnt * Wlin[j][c]
__global__ void final_kernel(const float* __restrict__ pooled, const float* __restrict__ cntf,
                             const float* __restrict__ Wlin, const float* __restrict__ blin,
                             float* __restrict__ out) {
    int g = blockIdx.x;
    int j = threadIdx.x;               // 0..31
    float inv = 1.0f / fmaxf(cntf[g], 1.0f);
    float sum = blin[j];
    const float* prow = pooled + g * 128;
    const float* wrow = Wlin + j * 128;
    for (int c = 0; c < 128; ++c) sum += prow[c] * inv * wrow[c];
    out[g * 32 + j] = sum;
}

extern "C" void kernel_launch(void* const* d_in, const int* in_sizes, int n_in,
                              void* d_out, int out_size, void* d_ws, size_t ws_size,
                              hipStream_t stream) {
    const float* x    = (const float*)d_in[0];
    const int*   src  = (const int*)d_in[1];
    const int*   dst  = ((const int*)d_in[1]) + N_EDGES;
    const int*   batch= (const int*)d_in[2];
    const float* W1l  = (const float*)d_in[3];
    const float* b1   = (const float*)d_in[4];
    const float* W1r  = (const float*)d_in[5];
    const float* W2l  = (const float*)d_in[6];
    const float* b2   = (const float*)d_in[7];
    const float* W2r  = (const float*)d_in[8];
    const float* Wlin = (const float*)d_in[9];
    const float* blin = (const float*)d_in[10];
    float* out = (float*)d_out;

    float* ws      = (float*)d_ws;
    float* msg     = ws;                      // 6,400,000
    float* h1      = msg + 6400000;           // 6,400,000
    float* h2      = h1 + 6400000;            // 6,400,000
    float* degf    = h2 + 6400000;            // 50,000
    float* invdeg  = degf + N_NODES;          // 50,000
    float* Wt1     = invdeg + N_NODES;        // 32,768
    float* Wt2     = Wt1 + 32768;             // 32,768
    float* pooled  = Wt2 + 32768;             // 8,192
    float* cntf    = pooled + N_GRAPHS * 128; // 64

    // zero scratch that is accumulated into (ws is poisoned before every call)
    hipMemsetAsync(msg, 0, (size_t)N_NODES * 128 * sizeof(float), stream);
    hipMemsetAsync(degf, 0, (size_t)N_NODES * sizeof(float), stream);
    hipMemsetAsync(pooled, 0, (size_t)(N_GRAPHS * 128 + N_GRAPHS) * sizeof(float), stream);

    // weight prep
    build_wt<<<128, 256, 0, stream>>>(W1l, W1r, Wt1);
    build_wt<<<128, 256, 0, stream>>>(W2l, W2r, Wt2);

    // degrees
    deg_kernel<<<(N_EDGES + 255) / 256, 256, 0, stream>>>(dst, degf, N_EDGES);
    invdeg_kernel<<<(N_NODES + 255) / 256, 256, 0, stream>>>(degf, invdeg, N_NODES);

    // layer 1
    scatter_kernel<<<(N_EDGES * 32) / 256, 256, 0, stream>>>(x, src, dst, msg, N_EDGES);
    sage_gemm<<<(N_NODES + BM - 1) / BM, 256, 0, stream>>>(msg, invdeg, x, Wt1, b1, h1, N_NODES);

    // layer 2
    hipMemsetAsync(msg, 0, (size_t)N_NODES * 128 * sizeof(float), stream);
    scatter_kernel<<<(N_EDGES * 32) / 256, 256, 0, stream>>>(h1, src, dst, msg, N_EDGES);
    sage_gemm<<<(N_NODES + BM - 1) / BM, 256, 0, stream>>>(msg, invdeg, h1, Wt2, b2, h2, N_NODES);

    // pool + final linear
    pool_kernel<<<(N_NODES + POOL_CHUNK - 1) / POOL_CHUNK, 128, 0, stream>>>(h2, batch, pooled, cntf, N_NODES);
    final_kernel<<<N_GRAPHS, 32, 0, stream>>>(pooled, cntf, Wlin, blin, out);
}

// Round 2
// 517.860 us; speedup vs baseline: 4.4822x; 4.4822x over previous
//
#include <hip/hip_runtime.h>

#define N_NODES 50000
#define N_EDGES 600000
#define N_GRAPHS 64
#define HID 128
#define OUT_C 32

// ---------------- weight prep: Wt[256][128], Wt[k][j] = k<128 ? Wl[j][k] : Wr[j][k-128]
__global__ void build_wt(const float* __restrict__ Wl, const float* __restrict__ Wr,
                         float* __restrict__ Wt) {
    int idx = blockIdx.x * 256 + threadIdx.x;   // 0..32767
    int k = idx >> 7, j = idx & 127;
    Wt[idx] = (k < 128) ? Wl[j * 128 + k] : Wr[j * 128 + (k - 128)];
}

// ---------------- CSR build
__global__ void deg_kernel(const int* __restrict__ dst, int* __restrict__ deg, int E) {
    int e = blockIdx.x * 256 + threadIdx.x;
    if (e < E) atomicAdd(&deg[dst[e]], 1);
}

#define SCAN_THREADS 1024
__global__ __launch_bounds__(SCAN_THREADS) void scan_kernel(
    const int* __restrict__ deg, int* __restrict__ rowptr, float* __restrict__ invdeg) {
    __shared__ int sums[SCAN_THREADS];
    const int t = threadIdx.x;
    const int chunk = (N_NODES + SCAN_THREADS - 1) / SCAN_THREADS;   // 49
    const int begin = t * chunk;
    const int end = min(begin + chunk, N_NODES);
    int s = 0;
    for (int i = begin; i < end; ++i) s += deg[i];
    sums[t] = s;
    __syncthreads();
    for (int off = 1; off < SCAN_THREADS; off <<= 1) {
        int v = 0;
        if (t >= off) v = sums[t - off];
        __syncthreads();
        if (t >= off) sums[t] += v;
        __syncthreads();
    }
    int run = (t == 0) ? 0 : sums[t - 1];   // exclusive prefix
    for (int i = begin; i < end; ++i) {
        rowptr[i] = run;
        int d = deg[i];
        invdeg[i] = 1.0f / fmaxf((float)d, 1.0f);
        run += d;
    }
    if (t == SCAN_THREADS - 1) rowptr[N_NODES] = run;
}

__global__ void fill_kernel(const int* __restrict__ src, const int* __restrict__ dst,
                            const int* __restrict__ rowptr, int* __restrict__ cursor,
                            int* __restrict__ eidx, int E) {
    int e = blockIdx.x * 256 + threadIdx.x;
    if (e < E) {
        int d = dst[e];
        int pos = atomicAdd(&cursor[d], 1);
        eidx[rowptr[d] + pos] = src[e];
    }
}

// ---------------- gather-aggregate: one wave per node, lane handles 2 channels.
// mean[n] = invdeg[n] * sum_{e in CSR[n]} feat[eidx[e]]
__global__ __launch_bounds__(256) void aggregate_kernel(
    const float* __restrict__ feat, const int* __restrict__ rowptr,
    const int* __restrict__ eidx, const float* __restrict__ invdeg,
    float* __restrict__ mean) {
    const int node = blockIdx.x * 4 + (threadIdx.x >> 6);
    if (node >= N_NODES) return;
    const int lane = threadIdx.x & 63;
    const int beg = rowptr[node];
    const int end = rowptr[node + 1];
    float2 acc = make_float2(0.f, 0.f);
    int i = beg;
    // 2-deep software pipeline on the src-index load
    int s_next = (i < end) ? eidx[i] : 0;
    for (; i < end; ++i) {
        const int s = s_next;
        if (i + 1 < end) s_next = eidx[i + 1];
        const float2 v = *(const float2*)(feat + (size_t)s * 128 + lane * 2);
        acc.x += v.x;
        acc.y += v.y;
    }
    const float sc = invdeg[node];
    acc.x *= sc;
    acc.y *= sc;
    *(float2*)(mean + (size_t)node * 128 + lane * 2) = acc;
}

// ---------------- fused SAGE layer GEMM:
// out[i][j] = relu(bias[j] + sum_{k<128} mean[i][k]*Wt[k][j] + sum_{k>=128} feat[i][k-128]*Wt[k][j])
// M=50000, N=128, K=256.  BM=64, BN=128, BK=32, 256 threads, 4x8 register tile.
#define BM 64
#define BN 128
#define BK 32

__global__ __launch_bounds__(256) void sage_gemm(
    const float* __restrict__ mean, const float* __restrict__ feat,
    const float* __restrict__ Wt, const float* __restrict__ bias,
    float* __restrict__ out, int M) {
    __shared__ float At[BK][BM + 4];
    __shared__ float Bt[BK][BN];

    const int tid = threadIdx.x;
    const int row0 = blockIdx.x * BM;
    const int tn = tid & 15;    // 16 threads over N, 8 cols each
    const int tm = tid >> 4;    // 16 threads over M, 4 rows each
    const int j0 = tn * 8;

    float acc[4][8];
#pragma unroll
    for (int m = 0; m < 4; ++m)
#pragma unroll
        for (int n = 0; n < 8; ++n) acc[m][n] = 0.0f;

    const int alr = tid >> 3;          // 0..31
    const int alc = (tid & 7) * 4;     // 0,4,..,28
    const int bbr = tid >> 5;          // 0..7
    const int bbc = (tid & 31) * 4;    // 0..124

    for (int k0 = 0; k0 < 256; k0 += BK) {
#pragma unroll
        for (int rr = 0; rr < 2; ++rr) {
            int r = alr + rr * 32;
            int gi = row0 + r;
            float4 v = make_float4(0.f, 0.f, 0.f, 0.f);
            if (gi < M) {
                const float* basep = (k0 < 128) ? (mean + (size_t)gi * 128 + k0 + alc)
                                                : (feat + (size_t)gi * 128 + (k0 - 128) + alc);
                v = *(const float4*)basep;
            }
            At[alc + 0][r] = v.x;
            At[alc + 1][r] = v.y;
            At[alc + 2][r] = v.z;
            At[alc + 3][r] = v.w;
        }
#pragma unroll
        for (int rr = 0; rr < 4; ++rr) {
            int r = bbr + rr * 8;
            *(float4*)&Bt[r][bbc] = *(const float4*)(Wt + (size_t)(k0 + r) * 128 + bbc);
        }
        __syncthreads();

#pragma unroll
        for (int kk = 0; kk < BK; ++kk) {
            const float4 av = *(const float4*)&At[kk][tm * 4];
            const float4 b0 = *(const float4*)&Bt[kk][j0];
            const float4 b1 = *(const float4*)&Bt[kk][j0 + 4];
            const float a4[4] = {av.x, av.y, av.z, av.w};
            const float b8[8] = {b0.x, b0.y, b0.z, b0.w, b1.x, b1.y, b1.z, b1.w};
#pragma unroll
            for (int m = 0; m < 4; ++m)
#pragma unroll
                for (int n = 0; n < 8; ++n) acc[m][n] += a4[m] * b8[n];
        }
        __syncthreads();
    }

    float bv[8];
#pragma unroll
    for (int n = 0; n < 8; ++n) bv[n] = bias[j0 + n];

#pragma unroll
    for (int m = 0; m < 4; ++m) {
        int gi = row0 + tm * 4 + m;
        if (gi < M) {
            float4 o0, o1;
            o0.x = fmaxf(acc[m][0] + bv[0], 0.f);
            o0.y = fmaxf(acc[m][1] + bv[1], 0.f);
            o0.z = fmaxf(acc[m][2] + bv[2], 0.f);
            o0.w = fmaxf(acc[m][3] + bv[3], 0.f);
            o1.x = fmaxf(acc[m][4] + bv[4], 0.f);
            o1.y = fmaxf(acc[m][5] + bv[5], 0.f);
            o1.z = fmaxf(acc[m][6] + bv[6], 0.f);
            o1.w = fmaxf(acc[m][7] + bv[7], 0.f);
            *(float4*)(out + (size_t)gi * 128 + j0) = o0;
            *(float4*)(out + (size_t)gi * 128 + j0 + 4) = o1;
        }
    }
}

// ---------------- pooling: batch is sorted; run-length accumulate, flush on change
#define POOL_CHUNK 128
__global__ void pool_kernel(const float* __restrict__ h, const int* __restrict__ batch,
                            float* __restrict__ pooled, float* __restrict__ cntf, int N) {
    int c = threadIdx.x;               // 0..127
    int n0 = blockIdx.x * POOL_CHUNK;
    int n1 = min(n0 + POOL_CHUNK, N);
    if (n0 >= N) return;
    float run = 0.0f;
    float runc = 0.0f;
    int curg = batch[n0];
    for (int n = n0; n < n1; ++n) {
        int g = batch[n];
        if (g != curg) {
            atomicAdd(&pooled[curg * 128 + c], run);
            if (c == 0) atomicAdd(&cntf[curg], runc);
            run = 0.0f; runc = 0.0f; curg = g;
        }
        run += h[(size_t)n * 128 + c];
        runc += 1.0f;
    }
    atomicAdd(&pooled[curg * 128 + c], run);
    if (c == 0) atomicAdd(&cntf[curg], runc);
}

// ---------------- final linear
__global__ void final_kernel(const float* __restrict__ pooled, const float* __restrict__ cntf,
                             const float* __restrict__ Wlin, const float* __restrict__ blin,
                             float* __restrict__ out) {
    int g = blockIdx.x;
    int j = threadIdx.x;               // 0..31
    float inv = 1.0f / fmaxf(cntf[g], 1.0f);
    float sum = blin[j];
    const float* prow = pooled + g * 128;
    const float* wrow = Wlin + j * 128;
    for (int c = 0; c < 128; ++c) sum += prow[c] * inv * wrow[c];
    out[g * 32 + j] = sum;
}

extern "C" void kernel_launch(void* const* d_in, const int* in_sizes, int n_in,
                              void* d_out, int out_size, void* d_ws, size_t ws_size,
                              hipStream_t stream) {
    const float* x    = (const float*)d_in[0];
    const int*   src  = (const int*)d_in[1];
    const int*   dst  = ((const int*)d_in[1]) + N_EDGES;
    const int*   batch= (const int*)d_in[2];
    const float* W1l  = (const float*)d_in[3];
    const float* b1   = (const float*)d_in[4];
    const float* W1r  = (const float*)d_in[5];
    const float* W2l  = (const float*)d_in[6];
    const float* b2   = (const float*)d_in[7];
    const float* W2r  = (const float*)d_in[8];
    const float* Wlin = (const float*)d_in[9];
    const float* blin = (const float*)d_in[10];
    float* out = (float*)d_out;

    float* ws      = (float*)d_ws;
    float* mean    = ws;                      // 6,400,000 f
    float* h1      = mean + 6400000;          // 6,400,000 f
    float* h2      = h1 + 6400000;            // 6,400,000 f
    int*   degi    = (int*)(h2 + 6400000);    // 50,000 i
    int*   rowptr  = degi + N_NODES;          // 50,001 i
    int*   cursor  = rowptr + N_NODES + 1;    // 50,000 i
    int*   eidx    = cursor + N_NODES;        // 600,000 i
    float* invdeg  = (float*)(eidx + N_EDGES);// 50,000 f
    float* Wt1     = invdeg + N_NODES;        // 32,768 f
    float* Wt2     = Wt1 + 32768;             // 32,768 f
    float* pooled  = Wt2 + 32768;             // 8,192 f
    float* cntf    = pooled + N_GRAPHS * 128; // 64 f

    // zero accumulated-into scratch (ws is re-poisoned before every call)
    hipMemsetAsync(degi, 0, (size_t)N_NODES * sizeof(int), stream);
    hipMemsetAsync(cursor, 0, (size_t)N_NODES * sizeof(int), stream);
    hipMemsetAsync(pooled, 0, (size_t)(N_GRAPHS * 128 + N_GRAPHS) * sizeof(float), stream);

    // weight prep
    build_wt<<<128, 256, 0, stream>>>(W1l, W1r, Wt1);
    build_wt<<<128, 256, 0, stream>>>(W2l, W2r, Wt2);

    // CSR build
    deg_kernel<<<(N_EDGES + 255) / 256, 256, 0, stream>>>(dst, degi, N_EDGES);
    scan_kernel<<<1, SCAN_THREADS, 0, stream>>>(degi, rowptr, invdeg);
    fill_kernel<<<(N_EDGES + 255) / 256, 256, 0, stream>>>(src, dst, rowptr, cursor, eidx, N_EDGES);

    // layer 1: aggregate (gather) + fused GEMM
    aggregate_kernel<<<(N_NODES + 3) / 4, 256, 0, stream>>>(x, rowptr, eidx, invdeg, mean);
    sage_gemm<<<(N_NODES + BM - 1) / BM, 256, 0, stream>>>(mean, x, Wt1, b1, h1, N_NODES);

    // layer 2
    aggregate_kernel<<<(N_NODES + 3) / 4, 256, 0, stream>>>(h1, rowptr, eidx, invdeg, mean);
    sage_gemm<<<(N_NODES + BM - 1) / BM, 256, 0, stream>>>(mean, h1, Wt2, b2, h2, N_NODES);

    // pool + final linear
    pool_kernel<<<(N_NODES + POOL_CHUNK - 1) / POOL_CHUNK, 128, 0, stream>>>(h2, batch, pooled, cntf, N_NODES);
    final_kernel<<<N_GRAPHS, 32, 0, stream>>>(pooled, cntf, Wlin, blin, out);
}

// Round 3
// 422.164 us; speedup vs baseline: 5.4983x; 1.2267x over previous
//
#include <hip/hip_runtime.h>

#define N_NODES 50000
#define N_EDGES 600000
#define N_GRAPHS 64
#define HID 128
#define OUT_C 32

#define SCAN_BLK 256
#define N_SCAN_BLOCKS ((N_NODES + SCAN_BLK - 1) / SCAN_BLK)   // 196

// ---------------- weight prep: Wt[256][128], Wt[k][j] = k<128 ? Wl[j][k] : Wr[j][k-128]
__global__ void build_wt(const float* __restrict__ Wl, const float* __restrict__ Wr,
                         float* __restrict__ Wt) {
    int idx = blockIdx.x * 256 + threadIdx.x;   // 0..32767
    int k = idx >> 7, j = idx & 127;
    Wt[idx] = (k < 128) ? Wl[j * 128 + k] : Wr[j * 128 + (k - 128)];
}

// ---------------- CSR build
__global__ void deg_kernel(const int* __restrict__ dst, int* __restrict__ deg, int E) {
    int e = blockIdx.x * 256 + threadIdx.x;
    if (e < E) atomicAdd(&deg[dst[e]], 1);
}

// phase 1: per-block sum of 256 degrees
__global__ __launch_bounds__(SCAN_BLK) void scan_blocksum(
    const int* __restrict__ deg, int* __restrict__ bsum) {
    __shared__ int s[SCAN_BLK];
    int i = blockIdx.x * SCAN_BLK + threadIdx.x;
    s[threadIdx.x] = (i < N_NODES) ? deg[i] : 0;
    __syncthreads();
    for (int off = SCAN_BLK / 2; off > 0; off >>= 1) {
        if (threadIdx.x < off) s[threadIdx.x] += s[threadIdx.x + off];
        __syncthreads();
    }
    if (threadIdx.x == 0) bsum[blockIdx.x] = s[0];
}

// phase 2: exclusive scan of the 196 block sums (single tiny block)
__global__ __launch_bounds__(256) void scan_boff(
    const int* __restrict__ bsum, int* __restrict__ boff, int* __restrict__ rowptr) {
    __shared__ int s[256];
    int t = threadIdx.x;
    int v = (t < N_SCAN_BLOCKS) ? bsum[t] : 0;
    s[t] = v;
    __syncthreads();
    for (int off = 1; off < 256; off <<= 1) {
        int u = (t >= off) ? s[t - off] : 0;
        __syncthreads();
        s[t] += u;
        __syncthreads();
    }
    if (t < N_SCAN_BLOCKS) boff[t] = s[t] - v;   // exclusive
    if (t == N_SCAN_BLOCKS - 1) rowptr[N_NODES] = s[t];
}

// phase 3: in-block exclusive scan + offset; emit rowptr and invdeg
__global__ __launch_bounds__(SCAN_BLK) void scan_emit(
    const int* __restrict__ deg, const int* __restrict__ boff,
    int* __restrict__ rowptr, float* __restrict__ invdeg) {
    __shared__ int s[SCAN_BLK];
    int i = blockIdx.x * SCAN_BLK + threadIdx.x;
    int t = threadIdx.x;
    int v = (i < N_NODES) ? deg[i] : 0;
    s[t] = v;
    __syncthreads();
    for (int off = 1; off < SCAN_BLK; off <<= 1) {
        int u = (t >= off) ? s[t - off] : 0;
        __syncthreads();
        s[t] += u;
        __syncthreads();
    }
    if (i < N_NODES) {
        rowptr[i] = boff[blockIdx.x] + s[t] - v;   // exclusive prefix
        invdeg[i] = 1.0f / fmaxf((float)v, 1.0f);
    }
}

__global__ void fill_kernel(const int* __restrict__ src, const int* __restrict__ dst,
                            const int* __restrict__ rowptr, int* __restrict__ cursor,
                            int* __restrict__ eidx, int E) {
    int e = blockIdx.x * 256 + threadIdx.x;
    if (e < E) {
        int d = dst[e];
        int pos = atomicAdd(&cursor[d], 1);
        eidx[rowptr[d] + pos] = src[e];
    }
}

// ---------------- gather-aggregate: one wave per node, lane handles 2 channels.
__global__ __launch_bounds__(256) void aggregate_kernel(
    const float* __restrict__ feat, const int* __restrict__ rowptr,
    const int* __restrict__ eidx, const float* __restrict__ invdeg,
    float* __restrict__ mean) {
    const int node = blockIdx.x * 4 + (threadIdx.x >> 6);
    if (node >= N_NODES) return;
    const int lane = threadIdx.x & 63;
    const int beg = rowptr[node];
    const int end = rowptr[node + 1];
    float2 acc = make_float2(0.f, 0.f);
    int i = beg;
    int s_next = (i < end) ? eidx[i] : 0;
    for (; i < end; ++i) {
        const int s = s_next;
        if (i + 1 < end) s_next = eidx[i + 1];
        const float2 v = *(const float2*)(feat + (size_t)s * 128 + lane * 2);
        acc.x += v.x;
        acc.y += v.y;
    }
    const float sc = invdeg[node];
    acc.x *= sc;
    acc.y *= sc;
    *(float2*)(mean + (size_t)node * 128 + lane * 2) = acc;
}

// ---------------- fused SAGE layer GEMM (M=50000, N=128, K=256)
#define BM 64
#define BN 128
#define BK 32

__global__ __launch_bounds__(256) void sage_gemm(
    const float* __restrict__ mean, const float* __restrict__ feat,
    const float* __restrict__ Wt, const float* __restrict__ bias,
    float* __restrict__ out, int M) {
    __shared__ float At[BK][BM + 4];
    __shared__ float Bt[BK][BN];

    const int tid = threadIdx.x;
    const int row0 = blockIdx.x * BM;
    const int tn = tid & 15;
    const int tm = tid >> 4;
    const int j0 = tn * 8;

    float acc[4][8];
#pragma unroll
    for (int m = 0; m < 4; ++m)
#pragma unroll
        for (int n = 0; n < 8; ++n) acc[m][n] = 0.0f;

    const int alr = tid >> 3;
    const int alc = (tid & 7) * 4;
    const int bbr = tid >> 5;
    const int bbc = (tid & 31) * 4;

    for (int k0 = 0; k0 < 256; k0 += BK) {
#pragma unroll
        for (int rr = 0; rr < 2; ++rr) {
            int r = alr + rr * 32;
            int gi = row0 + r;
            float4 v = make_float4(0.f, 0.f, 0.f, 0.f);
            if (gi < M) {
                const float* basep = (k0 < 128) ? (mean + (size_t)gi * 128 + k0 + alc)
                                                : (feat + (size_t)gi * 128 + (k0 - 128) + alc);
                v = *(const float4*)basep;
            }
            At[alc + 0][r] = v.x;
            At[alc + 1][r] = v.y;
            At[alc + 2][r] = v.z;
            At[alc + 3][r] = v.w;
        }
#pragma unroll
        for (int rr = 0; rr < 4; ++rr) {
            int r = bbr + rr * 8;
            *(float4*)&Bt[r][bbc] = *(const float4*)(Wt + (size_t)(k0 + r) * 128 + bbc);
        }
        __syncthreads();

#pragma unroll
        for (int kk = 0; kk < BK; ++kk) {
            const float4 av = *(const float4*)&At[kk][tm * 4];
            const float4 b0 = *(const float4*)&Bt[kk][j0];
            const float4 b1 = *(const float4*)&Bt[kk][j0 + 4];
            const float a4[4] = {av.x, av.y, av.z, av.w};
            const float b8[8] = {b0.x, b0.y, b0.z, b0.w, b1.x, b1.y, b1.z, b1.w};
#pragma unroll
            for (int m = 0; m < 4; ++m)
#pragma unroll
                for (int n = 0; n < 8; ++n) acc[m][n] += a4[m] * b8[n];
        }
        __syncthreads();
    }

    float bv[8];
#pragma unroll
    for (int n = 0; n < 8; ++n) bv[n] = bias[j0 + n];

#pragma unroll
    for (int m = 0; m < 4; ++m) {
        int gi = row0 + tm * 4 + m;
        if (gi < M) {
            float4 o0, o1;
            o0.x = fmaxf(acc[m][0] + bv[0], 0.f);
            o0.y = fmaxf(acc[m][1] + bv[1], 0.f);
            o0.z = fmaxf(acc[m][2] + bv[2], 0.f);
            o0.w = fmaxf(acc[m][3] + bv[3], 0.f);
            o1.x = fmaxf(acc[m][4] + bv[4], 0.f);
            o1.y = fmaxf(acc[m][5] + bv[5], 0.f);
            o1.z = fmaxf(acc[m][6] + bv[6], 0.f);
            o1.w = fmaxf(acc[m][7] + bv[7], 0.f);
            *(float4*)(out + (size_t)gi * 128 + j0) = o0;
            *(float4*)(out + (size_t)gi * 128 + j0 + 4) = o1;
        }
    }
}

// ---------------- pooling: batch is sorted; run-length accumulate, flush on change
#define POOL_CHUNK 128
__global__ void pool_kernel(const float* __restrict__ h, const int* __restrict__ batch,
                            float* __restrict__ pooled, float* __restrict__ cntf, int N) {
    int c = threadIdx.x;               // 0..127
    int n0 = blockIdx.x * POOL_CHUNK;
    int n1 = min(n0 + POOL_CHUNK, N);
    if (n0 >= N) return;
    float run = 0.0f;
    float runc = 0.0f;
    int curg = batch[n0];
    for (int n = n0; n < n1; ++n) {
        int g = batch[n];
        if (g != curg) {
            atomicAdd(&pooled[curg * 128 + c], run);
            if (c == 0) atomicAdd(&cntf[curg], runc);
            run = 0.0f; runc = 0.0f; curg = g;
        }
        run += h[(size_t)n * 128 + c];
        runc += 1.0f;
    }
    atomicAdd(&pooled[curg * 128 + c], run);
    if (c == 0) atomicAdd(&cntf[curg], runc);
}

// ---------------- final linear
__global__ void final_kernel(const float* __restrict__ pooled, const float* __restrict__ cntf,
                             const float* __restrict__ Wlin, const float* __restrict__ blin,
                             float* __restrict__ out) {
    int g = blockIdx.x;
    int j = threadIdx.x;               // 0..31
    float inv = 1.0f / fmaxf(cntf[g], 1.0f);
    float sum = blin[j];
    const float* prow = pooled + g * 128;
    const float* wrow = Wlin + j * 128;
    for (int c = 0; c < 128; ++c) sum += prow[c] * inv * wrow[c];
    out[g * 32 + j] = sum;
}

extern "C" void kernel_launch(void* const* d_in, const int* in_sizes, int n_in,
                              void* d_out, int out_size, void* d_ws, size_t ws_size,
                              hipStream_t stream) {
    const float* x    = (const float*)d_in[0];
    const int*   src  = (const int*)d_in[1];
    const int*   dst  = ((const int*)d_in[1]) + N_EDGES;
    const int*   batch= (const int*)d_in[2];
    const float* W1l  = (const float*)d_in[3];
    const float* b1   = (const float*)d_in[4];
    const float* W1r  = (const float*)d_in[5];
    const float* W2l  = (const float*)d_in[6];
    const float* b2   = (const float*)d_in[7];
    const float* W2r  = (const float*)d_in[8];
    const float* Wlin = (const float*)d_in[9];
    const float* blin = (const float*)d_in[10];
    float* out = (float*)d_out;

    float* ws      = (float*)d_ws;
    float* mean    = ws;                      // 6,400,000 f
    float* h1      = mean + 6400000;          // 6,400,000 f
    float* h2      = h1 + 6400000;            // 6,400,000 f
    int*   degi    = (int*)(h2 + 6400000);    // 50,000 i
    int*   rowptr  = degi + N_NODES;          // 50,001 i
    int*   cursor  = rowptr + N_NODES + 1;    // 50,000 i
    int*   eidx    = cursor + N_NODES;        // 600,000 i
    int*   bsum    = eidx + N_EDGES;          // 196 i
    int*   boff    = bsum + N_SCAN_BLOCKS;    // 196 i
    float* invdeg  = (float*)(boff + N_SCAN_BLOCKS); // 50,000 f
    float* Wt1     = invdeg + N_NODES;        // 32,768 f
    float* Wt2     = Wt1 + 32768;             // 32,768 f
    float* pooled  = Wt2 + 32768;             // 8,192 f
    float* cntf    = pooled + N_GRAPHS * 128; // 64 f

    // zero accumulated-into scratch (ws is re-poisoned before every call)
    hipMemsetAsync(degi, 0, (size_t)N_NODES * sizeof(int), stream);
    hipMemsetAsync(cursor, 0, (size_t)N_NODES * sizeof(int), stream);
    hipMemsetAsync(pooled, 0, (size_t)(N_GRAPHS * 128 + N_GRAPHS) * sizeof(float), stream);

    // weight prep
    build_wt<<<128, 256, 0, stream>>>(W1l, W1r, Wt1);
    build_wt<<<128, 256, 0, stream>>>(W2l, W2r, Wt2);

    // CSR build: coalesced 3-phase scan
    deg_kernel<<<(N_EDGES + 255) / 256, 256, 0, stream>>>(dst, degi, N_EDGES);
    scan_blocksum<<<N_SCAN_BLOCKS, SCAN_BLK, 0, stream>>>(degi, bsum);
    scan_boff<<<1, 256, 0, stream>>>(bsum, boff, rowptr);
    scan_emit<<<N_SCAN_BLOCKS, SCAN_BLK, 0, stream>>>(degi, boff, rowptr, invdeg);
    fill_kernel<<<(N_EDGES + 255) / 256, 256, 0, stream>>>(src, dst, rowptr, cursor, eidx, N_EDGES);

    // layer 1: aggregate (gather) + fused GEMM
    aggregate_kernel<<<(N_NODES + 3) / 4, 256, 0, stream>>>(x, rowptr, eidx, invdeg, mean);
    sage_gemm<<<(N_NODES + BM - 1) / BM, 256, 0, stream>>>(mean, x, Wt1, b1, h1, N_NODES);

    // layer 2
    aggregate_kernel<<<(N_NODES + 3) / 4, 256, 0, stream>>>(h1, rowptr, eidx, invdeg, mean);
    sage_gemm<<<(N_NODES + BM - 1) / BM, 256, 0, stream>>>(mean, h1, Wt2, b2, h2, N_NODES);

    // pool + final linear
    pool_kernel<<<(N_NODES + POOL_CHUNK - 1) / POOL_CHUNK, 128, 0, stream>>>(h2, batch, pooled, cntf, N_NODES);
    final_kernel<<<N_GRAPHS, 32, 0, stream>>>(pooled, cntf, Wlin, blin, out);
}

// Round 4
// 347.243 us; speedup vs baseline: 6.6846x; 1.2158x over previous
//
#include <hip/hip_runtime.h>

#define N_NODES 50000
#define N_EDGES 600000
#define N_GRAPHS 64
#define HID 128
#define OUT_C 32

#define SCAN_BLK 256
#define N_SCAN_BLOCKS ((N_NODES + SCAN_BLK - 1) / SCAN_BLK)   // 196

typedef __attribute__((ext_vector_type(8))) short short8;
typedef __attribute__((ext_vector_type(8))) unsigned short ushort8;
typedef __attribute__((ext_vector_type(4))) float f32x4;

// ---------------- weight prep: split-bf16 planes, n-major (B^T layout, contiguous k)
// Whn[n][k] = bf16_hi( k<128 ? Wl[n][k] : Wr[n][k-128] ), Wln = bf16 of residual
__global__ void build_w_bf16(const float* __restrict__ Wl, const float* __restrict__ Wr,
                             unsigned short* __restrict__ Whn, unsigned short* __restrict__ Wln) {
    int idx = blockIdx.x * 256 + threadIdx.x;   // 0..32767
    int n = idx >> 8, k = idx & 255;
    float a = (k < 128) ? Wl[n * 128 + k] : Wr[n * 128 + (k - 128)];
    unsigned int u = __float_as_uint(a);
    float hf = __uint_as_float(u & 0xFFFF0000u);
    float lf = a - hf;                 // exact (low mantissa bits)
    Whn[idx] = (unsigned short)(u >> 16);
    Wln[idx] = (unsigned short)(__float_as_uint(lf) >> 16);
}

// ---------------- CSR build
__global__ void deg_kernel(const int* __restrict__ dst, int* __restrict__ deg, int E) {
    int e = blockIdx.x * 256 + threadIdx.x;
    if (e < E) atomicAdd(&deg[dst[e]], 1);
}

__global__ __launch_bounds__(SCAN_BLK) void scan_blocksum(
    const int* __restrict__ deg, int* __restrict__ bsum) {
    __shared__ int s[SCAN_BLK];
    int i = blockIdx.x * SCAN_BLK + threadIdx.x;
    s[threadIdx.x] = (i < N_NODES) ? deg[i] : 0;
    __syncthreads();
    for (int off = SCAN_BLK / 2; off > 0; off >>= 1) {
        if (threadIdx.x < off) s[threadIdx.x] += s[threadIdx.x + off];
        __syncthreads();
    }
    if (threadIdx.x == 0) bsum[blockIdx.x] = s[0];
}

__global__ __launch_bounds__(256) void scan_boff(
    const int* __restrict__ bsum, int* __restrict__ boff, int* __restrict__ rowptr) {
    __shared__ int s[256];
    int t = threadIdx.x;
    int v = (t < N_SCAN_BLOCKS) ? bsum[t] : 0;
    s[t] = v;
    __syncthreads();
    for (int off = 1; off < 256; off <<= 1) {
        int u = (t >= off) ? s[t - off] : 0;
        __syncthreads();
        s[t] += u;
        __syncthreads();
    }
    if (t < N_SCAN_BLOCKS) boff[t] = s[t] - v;
    if (t == N_SCAN_BLOCKS - 1) rowptr[N_NODES] = s[t];
}

__global__ __launch_bounds__(SCAN_BLK) void scan_emit(
    const int* __restrict__ deg, const int* __restrict__ boff,
    int* __restrict__ rowptr, float* __restrict__ invdeg) {
    __shared__ int s[SCAN_BLK];
    int i = blockIdx.x * SCAN_BLK + threadIdx.x;
    int t = threadIdx.x;
    int v = (i < N_NODES) ? deg[i] : 0;
    s[t] = v;
    __syncthreads();
    for (int off = 1; off < SCAN_BLK; off <<= 1) {
        int u = (t >= off) ? s[t - off] : 0;
        __syncthreads();
        s[t] += u;
        __syncthreads();
    }
    if (i < N_NODES) {
        rowptr[i] = boff[blockIdx.x] + s[t] - v;
        invdeg[i] = 1.0f / fmaxf((float)v, 1.0f);
    }
}

__global__ void fill_kernel(const int* __restrict__ src, const int* __restrict__ dst,
                            const int* __restrict__ rowptr, int* __restrict__ cursor,
                            int* __restrict__ eidx, int E) {
    int e = blockIdx.x * 256 + threadIdx.x;
    if (e < E) {
        int d = dst[e];
        int pos = atomicAdd(&cursor[d], 1);
        eidx[rowptr[d] + pos] = src[e];
    }
}

// ---------------- gather-aggregate: one wave per node, lane handles 2 channels.
__global__ __launch_bounds__(256) void aggregate_kernel(
    const float* __restrict__ feat, const int* __restrict__ rowptr,
    const int* __restrict__ eidx, const float* __restrict__ invdeg,
    float* __restrict__ mean) {
    const int node = blockIdx.x * 4 + (threadIdx.x >> 6);
    if (node >= N_NODES) return;
    const int lane = threadIdx.x & 63;
    const int beg = rowptr[node];
    const int end = rowptr[node + 1];
    float2 acc = make_float2(0.f, 0.f);
    int i = beg;
    int s_next = (i < end) ? eidx[i] : 0;
    for (; i < end; ++i) {
        const int s = s_next;
        if (i + 1 < end) s_next = eidx[i + 1];
        const float2 v = *(const float2*)(feat + (size_t)s * 128 + lane * 2);
        acc.x += v.x;
        acc.y += v.y;
    }
    const float sc = invdeg[node];
    acc.x *= sc;
    acc.y *= sc;
    *(float2*)(mean + (size_t)node * 128 + lane * 2) = acc;
}

// ---------------- split-bf16 MFMA SAGE GEMM (M=50000, N=128, K=256)
// C = Ah@Bh + Ah@Bl + Al@Bh  (lo*lo dropped, ~2^-16 relative)
// block: 64x128 tile, 4 waves, wave w = rows w*16..w*16+15, all 8 N-tiles.
#define GBM 64
#define GBK 32
#define ASTR 48   // ushorts per LDS row (32 data + 16 pad; 96 B, 16B-aligned)
#define BSTR 48

__global__ __launch_bounds__(256) void sage_gemm_mfma(
    const float* __restrict__ mean, const float* __restrict__ feat,
    const unsigned short* __restrict__ Whn, const unsigned short* __restrict__ Wln,
    const float* __restrict__ bias, float* __restrict__ out, int M) {
    __shared__ __align__(16) unsigned short Ah[GBM][ASTR];
    __shared__ __align__(16) unsigned short Al[GBM][ASTR];
    __shared__ __align__(16) unsigned short Bh[128][BSTR];
    __shared__ __align__(16) unsigned short Bl[128][BSTR];

    const int tid = threadIdx.x;
    const int wave = tid >> 6;
    const int lane = tid & 63;
    const int l15 = lane & 15;
    const int quad = lane >> 4;
    const int row0 = blockIdx.x * GBM;

    f32x4 acc[8];
#pragma unroll
    for (int t = 0; t < 8; ++t) acc[t] = (f32x4){0.f, 0.f, 0.f, 0.f};

    const int ar = tid >> 2;          // A stage: row 0..63
    const int ac = (tid & 3) * 8;     // A stage: k offset {0,8,16,24}

    for (int k0 = 0; k0 < 256; k0 += GBK) {
        // ---- stage A: fp32 -> bf16 hi/lo planes
        {
            int gi = row0 + ar;
            float va[8];
            if (gi < M) {
                const float* p = (k0 < 128) ? (mean + (size_t)gi * 128 + k0 + ac)
                                            : (feat + (size_t)gi * 128 + (k0 - 128) + ac);
                float4 v0 = *(const float4*)p;
                float4 v1 = *(const float4*)(p + 4);
                va[0] = v0.x; va[1] = v0.y; va[2] = v0.z; va[3] = v0.w;
                va[4] = v1.x; va[5] = v1.y; va[6] = v1.z; va[7] = v1.w;
            } else {
#pragma unroll
                for (int i = 0; i < 8; ++i) va[i] = 0.f;
            }
            ushort8 h, l;
#pragma unroll
            for (int i = 0; i < 8; ++i) {
                unsigned int u = __float_as_uint(va[i]);
                float hf = __uint_as_float(u & 0xFFFF0000u);
                float lf = va[i] - hf;           // exact residual
                h[i] = (unsigned short)(u >> 16);
                l[i] = (unsigned short)(__float_as_uint(lf) >> 16);
            }
            *(ushort8*)&Ah[ar][ac] = h;
            *(ushort8*)&Al[ar][ac] = l;
        }
        // ---- stage B: copy pre-split ushort planes (16B chunks)
#pragma unroll
        for (int i = 0; i < 2; ++i) {
            int id = tid + i * 256;              // 0..511
            int n = id >> 2;
            int kc = (id & 3) * 8;
            *(ushort8*)&Bh[n][kc] = *(const ushort8*)(Whn + (size_t)n * 256 + k0 + kc);
            *(ushort8*)&Bl[n][kc] = *(const ushort8*)(Wln + (size_t)n * 256 + k0 + kc);
        }
        __syncthreads();

        const short8 a_h = *(const short8*)&Ah[wave * 16 + l15][quad * 8];
        const short8 a_l = *(const short8*)&Al[wave * 16 + l15][quad * 8];
#pragma unroll
        for (int t = 0; t < 8; ++t) {
            const short8 b_h = *(const short8*)&Bh[t * 16 + l15][quad * 8];
            const short8 b_l = *(const short8*)&Bl[t * 16 + l15][quad * 8];
            acc[t] = __builtin_amdgcn_mfma_f32_16x16x32_bf16(a_h, b_h, acc[t], 0, 0, 0);
            acc[t] = __builtin_amdgcn_mfma_f32_16x16x32_bf16(a_h, b_l, acc[t], 0, 0, 0);
            acc[t] = __builtin_amdgcn_mfma_f32_16x16x32_bf16(a_l, b_h, acc[t], 0, 0, 0);
        }
        __syncthreads();
    }

    // epilogue: row = row0 + wave*16 + quad*4 + r, col = t*16 + l15
#pragma unroll
    for (int r = 0; r < 4; ++r) {
        int gi = row0 + wave * 16 + quad * 4 + r;
        if (gi < M) {
#pragma unroll
            for (int t = 0; t < 8; ++t) {
                int col = t * 16 + l15;
                float v = acc[t][r] + bias[col];
                out[(size_t)gi * 128 + col] = fmaxf(v, 0.f);
            }
        }
    }
}

// ---------------- pooling: batch is sorted; run-length accumulate, flush on change
#define POOL_CHUNK 128
__global__ void pool_kernel(const float* __restrict__ h, const int* __restrict__ batch,
                            float* __restrict__ pooled, float* __restrict__ cntf, int N) {
    int c = threadIdx.x;               // 0..127
    int n0 = blockIdx.x * POOL_CHUNK;
    int n1 = min(n0 + POOL_CHUNK, N);
    if (n0 >= N) return;
    float run = 0.0f;
    float runc = 0.0f;
    int curg = batch[n0];
    for (int n = n0; n < n1; ++n) {
        int g = batch[n];
        if (g != curg) {
            atomicAdd(&pooled[curg * 128 + c], run);
            if (c == 0) atomicAdd(&cntf[curg], runc);
            run = 0.0f; runc = 0.0f; curg = g;
        }
        run += h[(size_t)n * 128 + c];
        runc += 1.0f;
    }
    atomicAdd(&pooled[curg * 128 + c], run);
    if (c == 0) atomicAdd(&cntf[curg], runc);
}

// ---------------- final linear
__global__ void final_kernel(const float* __restrict__ pooled, const float* __restrict__ cntf,
                             const float* __restrict__ Wlin, const float* __restrict__ blin,
                             float* __restrict__ out) {
    int g = blockIdx.x;
    int j = threadIdx.x;               // 0..31
    float inv = 1.0f / fmaxf(cntf[g], 1.0f);
    float sum = blin[j];
    const float* prow = pooled + g * 128;
    const float* wrow = Wlin + j * 128;
    for (int c = 0; c < 128; ++c) sum += prow[c] * inv * wrow[c];
    out[g * 32 + j] = sum;
}

extern "C" void kernel_launch(void* const* d_in, const int* in_sizes, int n_in,
                              void* d_out, int out_size, void* d_ws, size_t ws_size,
                              hipStream_t stream) {
    const float* x    = (const float*)d_in[0];
    const int*   src  = (const int*)d_in[1];
    const int*   dst  = ((const int*)d_in[1]) + N_EDGES;
    const int*   batch= (const int*)d_in[2];
    const float* W1l  = (const float*)d_in[3];
    const float* b1   = (const float*)d_in[4];
    const float* W1r  = (const float*)d_in[5];
    const float* W2l  = (const float*)d_in[6];
    const float* b2   = (const float*)d_in[7];
    const float* W2r  = (const float*)d_in[8];
    const float* Wlin = (const float*)d_in[9];
    const float* blin = (const float*)d_in[10];
    float* out = (float*)d_out;

    float* ws      = (float*)d_ws;
    float* mean    = ws;                       // 6,400,000 f
    float* h1      = mean + 6400000;           // 6,400,000 f
    float* h2      = h1 + 6400000;             // 6,400,000 f
    float* pooled  = h2 + 6400000;             // 8,192 f
    float* cntf    = pooled + N_GRAPHS * 128;  // 64 f
    float* invdeg  = cntf + 64;                // 50,000 f
    unsigned short* Whn1 = (unsigned short*)(invdeg + N_NODES);  // 32,768 us (16B-aligned)
    unsigned short* Wln1 = Whn1 + 32768;
    unsigned short* Whn2 = Wln1 + 32768;
    unsigned short* Wln2 = Whn2 + 32768;
    int*   degi    = (int*)(Wln2 + 32768);     // 50,000 i
    int*   rowptr  = degi + N_NODES;           // 50,001 i
    int*   cursor  = rowptr + N_NODES + 1;     // 50,000 i
    int*   eidx    = cursor + N_NODES;         // 600,000 i
    int*   bsum    = eidx + N_EDGES;           // 196 i
    int*   boff    = bsum + N_SCAN_BLOCKS;     // 196 i

    // zero accumulated-into scratch (ws is re-poisoned before every call)
    hipMemsetAsync(degi, 0, (size_t)N_NODES * sizeof(int), stream);
    hipMemsetAsync(cursor, 0, (size_t)N_NODES * sizeof(int), stream);
    hipMemsetAsync(pooled, 0, (size_t)(N_GRAPHS * 128 + N_GRAPHS) * sizeof(float), stream);

    // weight prep: split-bf16, n-major
    build_w_bf16<<<128, 256, 0, stream>>>(W1l, W1r, Whn1, Wln1);
    build_w_bf16<<<128, 256, 0, stream>>>(W2l, W2r, Whn2, Wln2);

    // CSR build: coalesced 3-phase scan
    deg_kernel<<<(N_EDGES + 255) / 256, 256, 0, stream>>>(dst, degi, N_EDGES);
    scan_blocksum<<<N_SCAN_BLOCKS, SCAN_BLK, 0, stream>>>(degi, bsum);
    scan_boff<<<1, 256, 0, stream>>>(bsum, boff, rowptr);
    scan_emit<<<N_SCAN_BLOCKS, SCAN_BLK, 0, stream>>>(degi, boff, rowptr, invdeg);
    fill_kernel<<<(N_EDGES + 255) / 256, 256, 0, stream>>>(src, dst, rowptr, cursor, eidx, N_EDGES);

    const int gemm_grid = (N_NODES + GBM - 1) / GBM;   // 782

    // layer 1
    aggregate_kernel<<<(N_NODES + 3) / 4, 256, 0, stream>>>(x, rowptr, eidx, invdeg, mean);
    sage_gemm_mfma<<<gemm_grid, 256, 0, stream>>>(mean, x, Whn1, Wln1, b1, h1, N_NODES);

    // layer 2
    aggregate_kernel<<<(N_NODES + 3) / 4, 256, 0, stream>>>(h1, rowptr, eidx, invdeg, mean);
    sage_gemm_mfma<<<gemm_grid, 256, 0, stream>>>(mean, h1, Whn2, Wln2, b2, h2, N_NODES);

    // pool + final linear
    pool_kernel<<<(N_NODES + POOL_CHUNK - 1) / POOL_CHUNK, 128, 0, stream>>>(h2, batch, pooled, cntf, N_NODES);
    final_kernel<<<N_GRAPHS, 32, 0, stream>>>(pooled, cntf, Wlin, blin, out);
}